// Round 2
// baseline (411.750 us; speedup 1.0000x reference)
//
#include <hip/hip_runtime.h>
#include <cstdint>
#include <cstddef>

#define NPTS 4096
#define BATCH 4
#define FEAT 256
#define KNN 32

// ---------------- workspace layout (bytes) ----------------
static constexpr size_t OFF_IDX  = 0;                          // int32 [B*N*K]  = 2 MB
static constexpr size_t OFF_HT   = 2u * 1024 * 1024;           // f32  [B*N*F]  = 16 MB
static constexpr size_t OFF_CNT  = OFF_HT + 16u * 1024 * 1024; // int32 [B*N]   = 64 KB
static constexpr size_t OFF_PART = OFF_CNT + 64u * 1024;       // f32  [64*512] = 128 KB
static constexpr size_t OFF_SC   = OFF_PART + 128u * 1024;     // f32 [256]
static constexpr size_t OFF_SH   = OFF_SC + 4096;              // f32 [256]

typedef unsigned long long u64;

static __device__ __forceinline__ u64 umin64(u64 a, u64 b) { return a < b ? a : b; }

// DPP-shifted copy of a u64 (two 32-bit halves); invalid lanes yield all-ones (+INF key)
template<int CTRL>
static __device__ __forceinline__ u64 dpp64(u64 x) {
    int lo = (int)(uint32_t)x;
    int hi = (int)(uint32_t)(x >> 32);
    int plo = __builtin_amdgcn_update_dpp(-1, lo, CTRL, 0xF, 0xF, false);
    int phi = __builtin_amdgcn_update_dpp(-1, hi, CTRL, 0xF, 0xF, false);
    return ((u64)(uint32_t)phi << 32) | (uint32_t)plo;
}

// branchless sorted insert into ascending 4-queue (q0 <= q1 <= q2 <= q3)
static __device__ __forceinline__ void ins4(u64& q0, u64& q1, u64& q2, u64& q3, u64 pk) {
    const bool b0 = pk < q0, b1 = pk < q1, b2 = pk < q2, b3 = pk < q3;
    q3 = b3 ? (b2 ? q2 : pk) : q3;
    q2 = b2 ? (b1 ? q1 : pk) : q2;
    q1 = b1 ? (b0 ? q0 : pk) : q1;
    q0 = b0 ? pk : q0;
}

// ---------------- KNN: one wave per (b, n) row; registers only, no LDS ----------------
__global__ __launch_bounds__(256) void knn_kernel(const float* __restrict__ xyz,
                                                  int* __restrict__ out_idx,
                                                  int* __restrict__ cnt) {
#pragma clang fp contract(off)
    const int lane = threadIdx.x & 63;
    const int n = blockIdx.x * 4 + (threadIdx.x >> 6);
    const int b = blockIdx.y;
    const float* xb = xyz + (size_t)b * 3 * NPTS;
    const float x0n = xb[n];
    const float x1n = xb[NPTS + n];
    const float sqn = x0n * x0n + x1n * x1n;  // round(x0^2)+round(x1^2), no contraction

    uint32_t kar[64];  // per-lane candidate keys (index implicit: m = i*64+lane)
    u64 q0 = ~0ull, q1 = ~0ull, q2 = ~0ull, q3 = ~0ull;
#pragma unroll
    for (int i = 0; i < 64; ++i) {
        const int m = i * 64 + lane;
        const float x0m = xb[m];
        const float x1m = xb[NPTS + m];
        const float sqm = x0m * x0m + x1m * x1m;
        const float p = __builtin_fmaf(x1n, x1m, x0n * x0m);  // fma-accumulated dot
        const float d = (sqm - 2.0f * p) + sqn;               // reference association
        uint32_t u = __float_as_uint(d);
        u = (u & 0x80000000u) ? ~u : (u | 0x80000000u);       // order-preserving map
        kar[i] = u;
        ins4(q0, q1, q2, q3, ((u64)u << 32) | (uint32_t)m);
    }

    int navail = 4;
    int* myout = out_idx + ((size_t)b * NPTS + n) * KNN;
#pragma unroll 1
    for (int k = 0; k < KNN; ++k) {
        // wave min over per-lane queue heads via DPP reduce; result lands in lane 63
        u64 v = q0;
        v = umin64(v, dpp64<0x111>(v));  // row_shr:1
        v = umin64(v, dpp64<0x112>(v));  // row_shr:2
        v = umin64(v, dpp64<0x114>(v));  // row_shr:4
        v = umin64(v, dpp64<0x118>(v));  // row_shr:8
        v = umin64(v, dpp64<0x142>(v));  // row_bcast:15
        v = umin64(v, dpp64<0x143>(v));  // row_bcast:31
        const uint32_t wlo = (uint32_t)__builtin_amdgcn_readlane((int)(uint32_t)v, 63);
        const uint32_t whi = (uint32_t)__builtin_amdgcn_readlane((int)(uint32_t)(v >> 32), 63);
        const u64 wkey = ((u64)whi << 32) | wlo;
        if (lane == 0) {
            myout[k] = (int)wlo;                     // winner index
            atomicAdd(&cnt[b * NPTS + (int)wlo], 1); // fused usage count
        }
        if (lane == (int)(wlo & 63u)) {  // owner pops its queue
            q0 = q1; q1 = q2; q2 = q3; q3 = ~0ull;
            if (--navail == 0) {
                // exact refill: all remaining candidates of this lane have pk > wkey
                q0 = q1 = q2 = q3 = ~0ull;
#pragma unroll
                for (int i = 0; i < 64; ++i) {
                    u64 pk = ((u64)kar[i] << 32) | (uint32_t)(i * 64 + lane);
                    pk = (pk > wkey) ? pk : ~0ull;
                    ins4(q0, q1, q2, q3, pk);
                }
                navail = 4;  // >= 32 candidates always remain per lane
            }
        }
    }
}

// ---------------- H = W @ feat[b] + bias, stored as Ht[b][n][f] ----------------
__global__ __launch_bounds__(256) void gemm_kernel(const float* __restrict__ feat,
                                                   const float* __restrict__ W,
                                                   const float* __restrict__ bias,
                                                   float* __restrict__ Ht) {
    __shared__ float As[64][64];  // [c][n_local]
    __shared__ float Bs[64][65];  // [c][f_local], padded
    const int b = blockIdx.z;
    const int n0 = blockIdx.x * 64;
    const int f0 = blockIdx.y * 64;
    const int t = threadIdx.x;
    const int tn = t % 16, tf = t / 16;
    float acc[4][4] = {};
    const float* fb = feat + (size_t)b * FEAT * NPTS;
    for (int c0 = 0; c0 < FEAT; c0 += 64) {
        for (int e = t; e < 4096; e += 256) {
            const int c = e >> 6, nl = e & 63;
            As[c][nl] = fb[(size_t)(c0 + c) * NPTS + n0 + nl];
        }
        for (int e = t; e < 4096; e += 256) {
            const int fl = e >> 6, c = e & 63;
            Bs[c][fl] = W[(size_t)(f0 + fl) * FEAT + c0 + c];
        }
        __syncthreads();
        for (int c = 0; c < 64; ++c) {
            float a[4], bb[4];
            for (int j = 0; j < 4; ++j) a[j] = As[c][tn * 4 + j];
            for (int i = 0; i < 4; ++i) bb[i] = Bs[c][tf * 4 + i];
            for (int j = 0; j < 4; ++j)
                for (int i = 0; i < 4; ++i)
                    acc[j][i] = __builtin_fmaf(a[j], bb[i], acc[j][i]);
        }
        __syncthreads();
    }
    for (int j = 0; j < 4; ++j) {
        const int n = n0 + tn * 4 + j;
        float4 v;
        v.x = acc[j][0] + bias[f0 + tf * 4 + 0];
        v.y = acc[j][1] + bias[f0 + tf * 4 + 1];
        v.z = acc[j][2] + bias[f0 + tf * 4 + 2];
        v.w = acc[j][3] + bias[f0 + tf * 4 + 3];
        *(float4*)(Ht + ((size_t)b * NPTS + n) * FEAT + f0 + tf * 4) = v;
    }
}

// ---------------- count-weighted per-channel partial sums ----------------
__global__ __launch_bounds__(256) void stats_partial(const float* __restrict__ Ht,
                                                     const int* __restrict__ cnt,
                                                     float* __restrict__ part) {
    const int b = blockIdx.y;
    const int n0 = blockIdx.x * 256;
    const int f = threadIdx.x;
    float s = 0.f, s2 = 0.f;
    for (int nl = 0; nl < 256; ++nl) {
        const int n = n0 + nl;
        const float c = (float)cnt[b * NPTS + n];
        const float v = Ht[((size_t)b * NPTS + n) * FEAT + f];
        s += c * v;
        s2 += c * v * v;
    }
    const int blk = b * 16 + blockIdx.x;
    part[blk * 512 + f] = s;
    part[blk * 512 + 256 + f] = s2;
}

__global__ __launch_bounds__(256) void stats_final(const float* __restrict__ part,
                                                   const float* __restrict__ gamma,
                                                   const float* __restrict__ beta,
                                                   float* __restrict__ sc,
                                                   float* __restrict__ sh) {
    const int f = threadIdx.x;
    float s = 0.f, s2 = 0.f;
    for (int blk = 0; blk < 64; ++blk) {
        s += part[blk * 512 + f];
        s2 += part[blk * 512 + 256 + f];
    }
    const float inv = 1.0f / (float)(BATCH * NPTS * KNN);
    const float mean = s * inv;
    const float var = s2 * inv - mean * mean;
    const float scale = gamma[f] * rsqrtf(var + 1e-5f);
    sc[f] = scale;
    sh[f] = beta[f] - scale * mean;
}

// ---------------- gather + affine + relu + max over K ----------------
#define NT 32
__global__ __launch_bounds__(256) void out_kernel(const float* __restrict__ Ht,
                                                  const int* __restrict__ idx,
                                                  const float* __restrict__ sc,
                                                  const float* __restrict__ sh,
                                                  float* __restrict__ out) {
    __shared__ float tile[NT][FEAT + 1];
    const int b = blockIdx.y;
    const int n0 = blockIdx.x * NT;
    const int f = threadIdx.x;
    const float scale = sc[f];
    const float shift = sh[f];
    const float* Hb = Ht + (size_t)b * NPTS * FEAT;
    const int* ib = idx + (size_t)b * NPTS * KNN;
    for (int nl = 0; nl < NT; ++nl) {
        const int n = n0 + nl;
        float acc = -1e30f;
        for (int k = 0; k < KNN; ++k) {
            const int u = ib[k * NPTS + n];  // uniform -> scalar load
            const float v = Hb[(size_t)u * FEAT + f];
            acc = fmaxf(acc, __builtin_fmaf(v, scale, shift));
        }
        tile[nl][f] = fmaxf(acc, 0.0f);
    }
    __syncthreads();
    const int nl2 = threadIdx.x & (NT - 1);
    const int fbase = threadIdx.x >> 5;  // 0..7
    for (int ff = 0; ff < FEAT; ff += 8) {
        const int f2 = fbase + ff;
        out[((size_t)b * FEAT + f2) * NPTS + n0 + nl2] = tile[nl2][f2];
    }
}

extern "C" void kernel_launch(void* const* d_in, const int* in_sizes, int n_in,
                              void* d_out, int out_size, void* d_ws, size_t ws_size,
                              hipStream_t stream) {
    (void)in_sizes; (void)n_in; (void)out_size; (void)ws_size;
    const float* xyz   = (const float*)d_in[0];
    const float* feat  = (const float*)d_in[1];
    const float* W     = (const float*)d_in[2];
    const float* bias  = (const float*)d_in[3];
    const float* gamma = (const float*)d_in[4];
    const float* beta  = (const float*)d_in[5];
    float* out = (float*)d_out;
    char* ws = (char*)d_ws;
    int*   idx  = (int*)(ws + OFF_IDX);
    float* Ht   = (float*)(ws + OFF_HT);
    int*   cnt  = (int*)(ws + OFF_CNT);
    float* part = (float*)(ws + OFF_PART);
    float* sc   = (float*)(ws + OFF_SC);
    float* sh   = (float*)(ws + OFF_SH);

    hipMemsetAsync(cnt, 0, BATCH * NPTS * sizeof(int), stream);
    knn_kernel<<<dim3(NPTS / 4, BATCH), 256, 0, stream>>>(xyz, idx, cnt);
    gemm_kernel<<<dim3(NPTS / 64, FEAT / 64, BATCH), 256, 0, stream>>>(feat, W, bias, Ht);
    stats_partial<<<dim3(NPTS / 256, BATCH), 256, 0, stream>>>(Ht, cnt, part);
    stats_final<<<1, 256, 0, stream>>>(part, gamma, beta, sc, sh);
    out_kernel<<<dim3(NPTS / NT, BATCH), 256, 0, stream>>>(Ht, idx, sc, sh, out);
}

// Round 3
// 271.472 us; speedup vs baseline: 1.5167x; 1.5167x over previous
//
#include <hip/hip_runtime.h>
#include <cstdint>
#include <cstddef>

#define NPTS 4096
#define BATCH 4
#define FEAT 256
#define KNN 32

// ---------------- workspace layout (bytes) ----------------
static constexpr size_t OFF_IDX  = 0;                          // int32 [B*N*K]  = 2 MB
static constexpr size_t OFF_HT   = 2u * 1024 * 1024;           // f32  [B*N*F]  = 16 MB
static constexpr size_t OFF_CNT  = OFF_HT + 16u * 1024 * 1024; // int32 [B*N]   = 64 KB
static constexpr size_t OFF_PART = OFF_CNT + 64u * 1024;       // f32  [64*512] = 128 KB
static constexpr size_t OFF_SC   = OFF_PART + 128u * 1024;     // f32 [256]
static constexpr size_t OFF_SH   = OFF_SC + 4096;              // f32 [256]

typedef unsigned long long u64;

static __device__ __forceinline__ u64 umin64(u64 a, u64 b) { return a < b ? a : b; }

// DPP-shifted copy of a u64 (two 32-bit halves); invalid lanes yield all-ones (+INF key)
template<int CTRL>
static __device__ __forceinline__ u64 dpp64(u64 x) {
    int lo = (int)(uint32_t)x;
    int hi = (int)(uint32_t)(x >> 32);
    int plo = __builtin_amdgcn_update_dpp(-1, lo, CTRL, 0xF, 0xF, false);
    int phi = __builtin_amdgcn_update_dpp(-1, hi, CTRL, 0xF, 0xF, false);
    return ((u64)(uint32_t)phi << 32) | (uint32_t)plo;
}

// branchless sorted insert into ascending 4-queue (q0 <= q1 <= q2 <= q3)
static __device__ __forceinline__ void ins4(u64& q0, u64& q1, u64& q2, u64& q3, u64 pk) {
    const bool b0 = pk < q0, b1 = pk < q1, b2 = pk < q2, b3 = pk < q3;
    q3 = b3 ? (b2 ? q2 : pk) : q3;
    q2 = b2 ? (b1 ? q1 : pk) : q2;
    q1 = b1 ? (b0 ? q0 : pk) : q1;
    q0 = b0 ? pk : q0;
}

// order-preserving f32 -> u32 map (identical bits to rounds 1/2)
static __device__ __forceinline__ uint32_t fmap(float d) {
    uint32_t u = __float_as_uint(d);
    return (u & 0x80000000u) ? ~u : (u | 0x80000000u);
}

// ---------------- KNN: one wave per (b, n) row; registers only, no LDS ----------------
// VGPR capped to 128 via launch_bounds -> 4 waves/SIMD.
__global__ __launch_bounds__(256, 4) void knn_kernel(const float* __restrict__ xyz,
                                                     int* __restrict__ out_idx,
                                                     int* __restrict__ cnt) {
#pragma clang fp contract(off)
    const int lane = threadIdx.x & 63;
    const int n = blockIdx.x * 4 + (threadIdx.x >> 6);
    const int b = blockIdx.y;
    const float* xb = xyz + (size_t)b * 3 * NPTS;
    const float x0n = xb[n];
    const float x1n = xb[NPTS + n];
    const float sqn = x0n * x0n + x1n * x1n;  // round(x0^2)+round(x1^2), no contraction

    // this lane's 64 candidates are contiguous: m = lane*64 + i
    const float* xr0 = xb + lane * 64;
    const float* xr1 = xb + NPTS + lane * 64;

    u64 q0 = ~0ull, q1 = ~0ull, q2 = ~0ull, q3 = ~0ull;
#pragma unroll 4
    for (int i0 = 0; i0 < 64; i0 += 4) {
        const float4 a0 = *(const float4*)(xr0 + i0);
        const float4 a1 = *(const float4*)(xr1 + i0);
        const float e0[4] = {a0.x, a0.y, a0.z, a0.w};
        const float e1[4] = {a1.x, a1.y, a1.z, a1.w};
#pragma unroll
        for (int j = 0; j < 4; ++j) {
            const float x0m = e0[j], x1m = e1[j];
            const float sqm = x0m * x0m + x1m * x1m;
            const float p = __builtin_fmaf(x1n, x1m, x0n * x0m);  // fma-accumulated dot
            const float d = (sqm - 2.0f * p) + sqn;               // reference association
            const int m = lane * 64 + i0 + j;
            ins4(q0, q1, q2, q3, ((u64)fmap(d) << 32) | (uint32_t)m);
        }
    }

    int navail = 4;
    int* myout = out_idx + ((size_t)b * NPTS + n) * KNN;
#pragma unroll 1
    for (int k = 0; k < KNN; ++k) {
        // wave min over per-lane queue heads via DPP reduce; result lands in lane 63
        u64 v = q0;
        v = umin64(v, dpp64<0x111>(v));  // row_shr:1
        v = umin64(v, dpp64<0x112>(v));  // row_shr:2
        v = umin64(v, dpp64<0x114>(v));  // row_shr:4
        v = umin64(v, dpp64<0x118>(v));  // row_shr:8
        v = umin64(v, dpp64<0x142>(v));  // row_bcast:15
        v = umin64(v, dpp64<0x143>(v));  // row_bcast:31
        const uint32_t wlo = (uint32_t)__builtin_amdgcn_readlane((int)(uint32_t)v, 63);
        const uint32_t whi = (uint32_t)__builtin_amdgcn_readlane((int)(uint32_t)(v >> 32), 63);
        const u64 wkey = ((u64)whi << 32) | wlo;
        if (lane == 0) {
            myout[k] = (int)wlo;                     // winner index
            atomicAdd(&cnt[b * NPTS + (int)wlo], 1); // fused usage count
        }
        if (lane == (int)(wlo >> 6)) {  // owner lane = m/64 pops its queue
            q0 = q1; q1 = q2; q2 = q3; q3 = ~0ull;
            if (--navail == 0) {
                // exact refill by recompute: remaining candidates have pk > wkey
                q0 = q1 = q2 = q3 = ~0ull;
#pragma unroll 4
                for (int i = 0; i < 64; ++i) {
                    const float x0m = xr0[i], x1m = xr1[i];
                    const float sqm = x0m * x0m + x1m * x1m;
                    const float p = __builtin_fmaf(x1n, x1m, x0n * x0m);
                    const float d = (sqm - 2.0f * p) + sqn;
                    u64 pk = ((u64)fmap(d) << 32) | (uint32_t)(lane * 64 + i);
                    pk = (pk > wkey) ? pk : ~0ull;
                    ins4(q0, q1, q2, q3, pk);
                }
                navail = 4;  // >= 32 candidates always remain per lane
            }
        }
    }
}

// ---------------- H = W @ feat[b] + bias, stored as Ht[b][n][f] ----------------
__global__ __launch_bounds__(256) void gemm_kernel(const float* __restrict__ feat,
                                                   const float* __restrict__ W,
                                                   const float* __restrict__ bias,
                                                   float* __restrict__ Ht) {
    __shared__ float As[64][64];  // [c][n_local]
    __shared__ float Bs[64][65];  // [c][f_local], padded
    const int b = blockIdx.z;
    const int n0 = blockIdx.x * 64;
    const int f0 = blockIdx.y * 64;
    const int t = threadIdx.x;
    const int tn = t % 16, tf = t / 16;
    float acc[4][4] = {};
    const float* fb = feat + (size_t)b * FEAT * NPTS;
    for (int c0 = 0; c0 < FEAT; c0 += 64) {
        for (int e = t; e < 4096; e += 256) {
            const int c = e >> 6, nl = e & 63;
            As[c][nl] = fb[(size_t)(c0 + c) * NPTS + n0 + nl];
        }
        for (int e = t; e < 4096; e += 256) {
            const int fl = e >> 6, c = e & 63;
            Bs[c][fl] = W[(size_t)(f0 + fl) * FEAT + c0 + c];
        }
        __syncthreads();
        for (int c = 0; c < 64; ++c) {
            float a[4], bb[4];
            for (int j = 0; j < 4; ++j) a[j] = As[c][tn * 4 + j];
            for (int i = 0; i < 4; ++i) bb[i] = Bs[c][tf * 4 + i];
            for (int j = 0; j < 4; ++j)
                for (int i = 0; i < 4; ++i)
                    acc[j][i] = __builtin_fmaf(a[j], bb[i], acc[j][i]);
        }
        __syncthreads();
    }
    for (int j = 0; j < 4; ++j) {
        const int n = n0 + tn * 4 + j;
        float4 v;
        v.x = acc[j][0] + bias[f0 + tf * 4 + 0];
        v.y = acc[j][1] + bias[f0 + tf * 4 + 1];
        v.z = acc[j][2] + bias[f0 + tf * 4 + 2];
        v.w = acc[j][3] + bias[f0 + tf * 4 + 3];
        *(float4*)(Ht + ((size_t)b * NPTS + n) * FEAT + f0 + tf * 4) = v;
    }
}

// ---------------- count-weighted per-channel partial sums ----------------
__global__ __launch_bounds__(256) void stats_partial(const float* __restrict__ Ht,
                                                     const int* __restrict__ cnt,
                                                     float* __restrict__ part) {
    const int b = blockIdx.y;
    const int n0 = blockIdx.x * 256;
    const int f = threadIdx.x;
    float s = 0.f, s2 = 0.f;
    for (int nl = 0; nl < 256; ++nl) {
        const int n = n0 + nl;
        const float c = (float)cnt[b * NPTS + n];
        const float v = Ht[((size_t)b * NPTS + n) * FEAT + f];
        s += c * v;
        s2 += c * v * v;
    }
    const int blk = b * 16 + blockIdx.x;
    part[blk * 512 + f] = s;
    part[blk * 512 + 256 + f] = s2;
}

__global__ __launch_bounds__(256) void stats_final(const float* __restrict__ part,
                                                   const float* __restrict__ gamma,
                                                   const float* __restrict__ beta,
                                                   float* __restrict__ sc,
                                                   float* __restrict__ sh) {
    const int f = threadIdx.x;
    float s = 0.f, s2 = 0.f;
    for (int blk = 0; blk < 64; ++blk) {
        s += part[blk * 512 + f];
        s2 += part[blk * 512 + 256 + f];
    }
    const float inv = 1.0f / (float)(BATCH * NPTS * KNN);
    const float mean = s * inv;
    const float var = s2 * inv - mean * mean;
    const float scale = gamma[f] * rsqrtf(var + 1e-5f);
    sc[f] = scale;
    sh[f] = beta[f] - scale * mean;
}

// ---------------- gather + affine + relu + max over K ----------------
#define NT 32
__global__ __launch_bounds__(256) void out_kernel(const float* __restrict__ Ht,
                                                  const int* __restrict__ idx,
                                                  const float* __restrict__ sc,
                                                  const float* __restrict__ sh,
                                                  float* __restrict__ out) {
    __shared__ float tile[NT][FEAT + 1];
    const int b = blockIdx.y;
    const int n0 = blockIdx.x * NT;
    const int f = threadIdx.x;
    const float scale = sc[f];
    const float shift = sh[f];
    const float* Hb = Ht + (size_t)b * NPTS * FEAT;
    const int* ib = idx + (size_t)b * NPTS * KNN;
    for (int nl = 0; nl < NT; ++nl) {
        const int n = n0 + nl;
        float acc = -1e30f;
        for (int k = 0; k < KNN; ++k) {
            const int u = ib[k * NPTS + n];  // uniform -> scalar load
            const float v = Hb[(size_t)u * FEAT + f];
            acc = fmaxf(acc, __builtin_fmaf(v, scale, shift));
        }
        tile[nl][f] = fmaxf(acc, 0.0f);
    }
    __syncthreads();
    const int nl2 = threadIdx.x & (NT - 1);
    const int fbase = threadIdx.x >> 5;  // 0..7
    for (int ff = 0; ff < FEAT; ff += 8) {
        const int f2 = fbase + ff;
        out[((size_t)b * FEAT + f2) * NPTS + n0 + nl2] = tile[nl2][f2];
    }
}

extern "C" void kernel_launch(void* const* d_in, const int* in_sizes, int n_in,
                              void* d_out, int out_size, void* d_ws, size_t ws_size,
                              hipStream_t stream) {
    (void)in_sizes; (void)n_in; (void)out_size; (void)ws_size;
    const float* xyz   = (const float*)d_in[0];
    const float* feat  = (const float*)d_in[1];
    const float* W     = (const float*)d_in[2];
    const float* bias  = (const float*)d_in[3];
    const float* gamma = (const float*)d_in[4];
    const float* beta  = (const float*)d_in[5];
    float* out = (float*)d_out;
    char* ws = (char*)d_ws;
    int*   idx  = (int*)(ws + OFF_IDX);
    float* Ht   = (float*)(ws + OFF_HT);
    int*   cnt  = (int*)(ws + OFF_CNT);
    float* part = (float*)(ws + OFF_PART);
    float* sc   = (float*)(ws + OFF_SC);
    float* sh   = (float*)(ws + OFF_SH);

    hipMemsetAsync(cnt, 0, BATCH * NPTS * sizeof(int), stream);
    knn_kernel<<<dim3(NPTS / 4, BATCH), 256, 0, stream>>>(xyz, idx, cnt);
    gemm_kernel<<<dim3(NPTS / 64, FEAT / 64, BATCH), 256, 0, stream>>>(feat, W, bias, Ht);
    stats_partial<<<dim3(NPTS / 256, BATCH), 256, 0, stream>>>(Ht, cnt, part);
    stats_final<<<1, 256, 0, stream>>>(part, gamma, beta, sc, sh);
    out_kernel<<<dim3(NPTS / NT, BATCH), 256, 0, stream>>>(Ht, idx, sc, sh, out);
}